// Round 6
// baseline (345.134 us; speedup 1.0000x reference)
//
#include <hip/hip_runtime.h>
#include <cstdint>
#include <cstddef>

#define B_ 2
#define T_ 2048
#define D_ 2048
#define HQ_ 16
#define HKV_ 8
#define HD_ 128

typedef __attribute__((ext_vector_type(8))) short short8;
typedef __attribute__((ext_vector_type(8))) unsigned short ushort8;
typedef __attribute__((ext_vector_type(4))) float f32x4;
typedef __attribute__((ext_vector_type(2))) unsigned short ushort2v;
typedef __attribute__((ext_vector_type(4))) unsigned short ushort4v;
typedef __attribute__((ext_vector_type(2))) float float2v;
typedef __attribute__((ext_vector_type(4))) float float4v;

__device__ __forceinline__ unsigned short f2bf(float f) {
  unsigned int u = __builtin_bit_cast(unsigned int, f);
  u += 0x7fffu + ((u >> 16) & 1u);
  return (unsigned short)(u >> 16);
}
__device__ __forceinline__ float bf2f(unsigned short h) {
  unsigned int u = ((unsigned int)h) << 16;
  return __builtin_bit_cast(float, u);
}

#if defined(__has_builtin)
#if __has_builtin(__builtin_amdgcn_global_load_lds)
#define HAS_GLL 1
#endif
#endif
#ifndef HAS_GLL
#define HAS_GLL 0
#endif

// async global->LDS, 16B per lane; LDS dest = base (wave-uniform) + lane*16
__device__ __forceinline__ void gll16(const void* g, void* l) {
#if HAS_GLL
  __builtin_amdgcn_global_load_lds((const __attribute__((address_space(1))) void*)g,
                                   (__attribute__((address_space(3))) void*)l, 16, 0, 0);
#else
  *(ushort8*)((char*)l + (threadIdx.x & 63) * 16) = *(const ushort8*)g;
#endif
}

// ---------------- fused cast f32 -> bf16 for all five tensors (one launch) ----------------
__global__ __launch_bounds__(256) void cast_all(const float* __restrict__ x,
                                                const float* __restrict__ wq,
                                                const float* __restrict__ wk,
                                                const float* __restrict__ wv,
                                                const float* __restrict__ wo,
                                                unsigned short* __restrict__ xb,
                                                unsigned short* __restrict__ wqkv,
                                                unsigned short* __restrict__ wob) {
  int i = (blockIdx.x * 256 + threadIdx.x) * 4;
  if (i >= 20971520) return;
  const float* s;
  unsigned short* d;
  int soff, doff;
  if (i < 8388608)       { s = x;  soff = i;            d = xb;   doff = i; }
  else if (i < 12582912) { s = wq; soff = i - 8388608;  d = wqkv; doff = i - 8388608; }
  else if (i < 14680064) { s = wk; soff = i - 12582912; d = wqkv; doff = i - 8388608; }
  else if (i < 16777216) { s = wv; soff = i - 14680064; d = wqkv; doff = i - 8388608; }
  else                   { s = wo; soff = i - 16777216; d = wob;  doff = i - 16777216; }
  float4v v = *(const float4v*)(s + soff);
  ushort4v o; o.x = f2bf(v.x); o.y = f2bf(v.y); o.z = f2bf(v.z); o.w = f2bf(v.w);
  *(ushort4v*)(d + doff) = o;
}

// ================= GEMM v3: BMx256 tile, BK=64, 8 waves, 8-phase pipelined =================
// (unchanged from round 5 — verified; see round-3 proof)
#define PH_SYNC { __builtin_amdgcn_s_barrier(); \
                  asm volatile("s_waitcnt lgkmcnt(0)" ::: "memory"); \
                  __builtin_amdgcn_sched_barrier(0); \
                  __builtin_amdgcn_s_setprio(1); }
#define PH_END  { __builtin_amdgcn_s_setprio(0); \
                  __builtin_amdgcn_s_barrier(); \
                  __builtin_amdgcn_sched_barrier(0); }

#define LDA(BUF, QM) { \
  _Pragma("unroll") for (int ii = 0; ii < BM/64; ii++) { \
    _Pragma("unroll") for (int ks = 0; ks < 2; ks++) \
      a[ii][ks] = *(const short8*)&Abuf[BUF][((QM)*(BM/2) + wm*(BM/4) + ii*16 + c)*64 + (((ks*4+g)^cs)*8)]; } }

#define LDB(BUF, QN, BB) { \
  _Pragma("unroll") for (int jj = 0; jj < 2; jj++) { \
    _Pragma("unroll") for (int ks = 0; ks < 2; ks++) \
      BB[jj][ks] = *(const short8*)&Bbuf[BUF][((QN)*128 + wn*32 + jj*16 + c)*64 + (((ks*4+g)^cs)*8)]; } }

#define MM(QM, QN, BB) { \
  _Pragma("unroll") for (int ii = 0; ii < BM/64; ii++) { \
    _Pragma("unroll") for (int jj = 0; jj < 2; jj++) { \
      f32x4 t_ = __builtin_amdgcn_mfma_f32_16x16x32_bf16(a[ii][0], BB[jj][0], acc[(QM)*(BM/64)+ii][(QN)*2+jj], 0, 0, 0); \
      acc[(QM)*(BM/64)+ii][(QN)*2+jj] = __builtin_amdgcn_mfma_f32_16x16x32_bf16(a[ii][1], BB[jj][1], t_, 0, 0, 0); } } }

template<int BM, int M, int N, int K, bool BF16_OUT>
__global__ __launch_bounds__(512, 2) void gemm8(const unsigned short* __restrict__ A,
                                                const unsigned short* __restrict__ W,
                                                void* __restrict__ Cout) {
  __shared__ __align__(16) unsigned short Abuf[2][BM * 64];
  __shared__ __align__(16) unsigned short Bbuf[2][256 * 64];
  const int tid = threadIdx.x;
  const int lane = tid & 63;
  const int wv = tid >> 6;        // 0..7
  const int g = lane >> 4;        // 0..3
  const int c = lane & 15;
  const int cs = c & 7;
  const int wm = wv >> 2;         // 0..1
  const int wn = wv & 3;          // 0..3

  constexpr int SH_Q = (BM == 256) ? 7 : 6;   // log2(BM/2)
  constexpr int SH_W = SH_Q - 1;              // log2(BM/4)

  constexpr int NT = N / 256;
  constexpr int NWG = (M / BM) * NT;
  constexpr int CHUNK = NWG / 8;  // NWG % 8 == 0 for both instantiations
  const int bid = blockIdx.x;
  const int swz = (bid & 7) * CHUNK + (bid >> 3);
  const int m0 = (swz / NT) * BM;
  const int n0 = (swz % NT) * 256;

  const int prl = wv * 8 + (lane >> 3);   // physical row offset within call
  const int scl = lane & 7;               // stored chunk slot
#define STA(BUF, P0, KO) { \
    int pr_ = (P0) + prl; \
    int lr_ = ((pr_ >> SH_W) & 1) * (BM/2) + ((pr_ >> SH_Q) & 1) * (BM/4) + (pr_ & (BM/4 - 1)); \
    int lc_ = (scl ^ (pr_ & 7)) * 8; \
    gll16(&A[(size_t)(m0 + lr_) * K + (KO) + lc_], &Abuf[BUF][(P0) * 64 + wv * 512]); }
#define STB(BUF, P0, KO) { \
    int pr_ = (P0) + prl; \
    int lr_ = ((pr_ >> 5) & 3) * 64 + ((pr_ >> 7) & 1) * 32 + (pr_ & 31); \
    int lc_ = (scl ^ (pr_ & 7)) * 8; \
    gll16(&W[(size_t)(n0 + lr_) * K + (KO) + lc_], &Bbuf[BUF][(P0) * 64 + wv * 512]); }

#define STAGE_PH2(BUF, KO) { if constexpr (BM == 256) { STA(BUF, 0, KO); STA(BUF, 64, KO); } \
                             else { STA(BUF, 0, KO); } \
                             STB(BUF, 0, KO); STB(BUF, 64, KO); }
#define STAGE_PH3(BUF, KO) { STB(BUF, 128, KO); STB(BUF, 192, KO); }
#define STAGE_PH4(BUF, KO) { if constexpr (BM == 256) { STA(BUF, 128, KO); STA(BUF, 192, KO); } \
                             else { STA(BUF, 64, KO); } }
#define VMW { if constexpr (BM == 256) { asm volatile("s_waitcnt vmcnt(8)" ::: "memory"); } \
              else { asm volatile("s_waitcnt vmcnt(6)" ::: "memory"); } }

  short8 a[BM/64][2], b0[2][2], b1[2][2];
  f32x4 acc[BM/32][4];
#pragma unroll
  for (int i = 0; i < BM/32; i++)
#pragma unroll
    for (int j = 0; j < 4; j++) acc[i][j] = (f32x4)0.0f;

  // prologue: fully stage K-tiles 0 (buf0) and 1 (buf1)
  STAGE_PH2(0, 0); STAGE_PH3(0, 0); STAGE_PH4(0, 0);
  STAGE_PH2(1, 64); STAGE_PH3(1, 64); STAGE_PH4(1, 64);
  VMW;                               // K-tile 0 landed
  __builtin_amdgcn_s_barrier();

  constexpr int NITER = K / 128;   // 16
  for (int it = 0; it < NITER - 1; ++it) {
    const int k2 = it * 128 + 128;   // K-tile 2it+2 -> buf0
    const int k3 = k2 + 64;          // K-tile 2it+3 -> buf1
    LDA(0, 0); LDB(0, 0, b0);
    PH_SYNC; MM(0, 0, b0); PH_END;
    LDB(0, 1, b1);
    STAGE_PH2(0, k2);
    PH_SYNC; MM(0, 1, b1); PH_END;
    LDA(0, 1);
    STAGE_PH3(0, k2);
    PH_SYNC; MM(1, 1, b1); PH_END;
    STAGE_PH4(0, k2);
    VMW;
    PH_SYNC; MM(1, 0, b0); PH_END;
    LDA(1, 0); LDB(1, 0, b0);
    PH_SYNC; MM(0, 0, b0); PH_END;
    LDB(1, 1, b1);
    STAGE_PH2(1, k3);
    PH_SYNC; MM(0, 1, b1); PH_END;
    LDA(1, 1);
    STAGE_PH3(1, k3);
    PH_SYNC; MM(1, 1, b1); PH_END;
    STAGE_PH4(1, k3);
    VMW;
    PH_SYNC; MM(1, 0, b0); PH_END;
  }
  // peeled final iteration (no stages; ph4 drains)
  LDA(0, 0); LDB(0, 0, b0); PH_SYNC; MM(0, 0, b0); PH_END;
  LDB(0, 1, b1);            PH_SYNC; MM(0, 1, b1); PH_END;
  LDA(0, 1);                PH_SYNC; MM(1, 1, b1); PH_END;
  asm volatile("s_waitcnt vmcnt(0)" ::: "memory");
  PH_SYNC; MM(1, 0, b0); PH_END;
  LDA(1, 0); LDB(1, 0, b0); PH_SYNC; MM(0, 0, b0); PH_END;
  LDB(1, 1, b1);            PH_SYNC; MM(0, 1, b1); PH_END;
  LDA(1, 1);                PH_SYNC; MM(1, 1, b1); PH_END;
  PH_SYNC; MM(1, 0, b0); PH_END;

  // epilogue: C/D layout col=lane&15, row=g*4+r (verified)
#pragma unroll
  for (int I = 0; I < BM/32; I++)
#pragma unroll
    for (int J = 0; J < 4; J++)
#pragma unroll
      for (int r = 0; r < 4; r++) {
        int row = m0 + wm * (BM/2) + I * 16 + g * 4 + r;
        int col = n0 + wn * 64 + J * 16 + c;
        if (BF16_OUT)
          ((unsigned short*)Cout)[(size_t)row * N + col] = f2bf(acc[I][J][r]);
        else
          ((float*)Cout)[(size_t)row * N + col] = acc[I][J][r];
      }
#undef STA
#undef STB
#undef STAGE_PH2
#undef STAGE_PH3
#undef STAGE_PH4
#undef VMW
}

// ---------------- RMSNorm + RoPE v2: one block per (b,t), cos/sin in regs ----------------
__global__ __launch_bounds__(256) void qk_norm_rope(const unsigned short* __restrict__ qkv,
                                                    const float* __restrict__ cosT,
                                                    const float* __restrict__ sinT,
                                                    const float* __restrict__ q_scale,
                                                    const float* __restrict__ k_scale,
                                                    unsigned short* __restrict__ Qb,
                                                    unsigned short* __restrict__ Kb) {
  const int tid = threadIdx.x;
  const int lane = tid & 63;
  const int wv = tid >> 6;
  const int row = blockIdx.x;   // b*T + t
  const int b = row >> 11;
  const int t = row & 2047;
  const int d0 = lane * 2;

  const float2v cs = *(const float2v*)&cosT[t * 128 + d0];
  const float2v sn = *(const float2v*)&sinT[t * 128 + d0];
  const float2v qsc = *(const float2v*)&q_scale[d0];
  const float2v ksc = *(const float2v*)&k_scale[d0];
  const float sgn = (lane < 32) ? -1.0f : 1.0f;
  const unsigned short* base = qkv + (size_t)row * 4096;

#pragma unroll
  for (int s6 = 0; s6 < 6; s6++) {
    const int slot = wv * 6 + s6;
    const bool isQ = slot < 16;
    const unsigned short* src = base + (isQ ? slot * 128 : 2048 + (slot - 16) * 128);
    ushort2v u = *(const ushort2v*)&src[d0];
    float x0 = bf2f(u.x), x1 = bf2f(u.y);
    float ss = x0 * x0 + x1 * x1;
    ss += __shfl_xor(ss, 1);  ss += __shfl_xor(ss, 2);  ss += __shfl_xor(ss, 4);
    ss += __shfl_xor(ss, 8);  ss += __shfl_xor(ss, 16); ss += __shfl_xor(ss, 32);
    float rinv = rsqrtf(ss * (1.0f / 128.0f) + 1e-6f);
    float2v scv = isQ ? qsc : ksc;
    float xn0 = x0 * rinv * scv.x;
    float xn1 = x1 * rinv * scv.y;
    float o0 = __shfl_xor(xn0, 32);
    float o1 = __shfl_xor(xn1, 32);
    float r0v = xn0 * cs.x + sgn * o0 * sn.x;
    float r1v = xn1 * cs.y + sgn * o1 * sn.y;
    ushort2v out; out.x = f2bf(r0v); out.y = f2bf(r1v);
    unsigned short* dst;
    if (isQ) dst = Qb + ((size_t)(b * HQ_ + slot) * T_ + t) * HD_;
    else     dst = Kb + ((size_t)(b * HKV_ + (slot - 16)) * T_ + t) * HD_;
    *(ushort2v*)&dst[d0] = out;
  }
}

// ---------------- V transpose: (b,t,kv,d) -> Vt[b,kv,d,t] bf16 ----------------
__global__ __launch_bounds__(256) void v_transpose(const unsigned short* __restrict__ qkv,
                                                   unsigned short* __restrict__ Vt) {
  __shared__ unsigned short lds[128 * 65];
  const int tid = threadIdx.x;
  const int blk = blockIdx.x;
  const int tblk = blk & 31;
  const int kv = (blk >> 5) & 7;
  const int b = blk >> 8;
  const int t0 = tblk * 64;
  const int r = tid >> 2;
  const int seg = tid & 3;
  const unsigned short* src = qkv + (size_t)(b * T_ + t0 + r) * 4096 + 3072 + kv * 128;
  for (int i = 0; i < 4; i++) {
    int cc = seg * 32 + i * 8;
    ushort8 v = *(const ushort8*)&src[cc];
    for (int q = 0; q < 8; q++) lds[(cc + q) * 65 + r] = v[q];
  }
  __syncthreads();
  const int cI = tid >> 1;
  const int rs = (tid & 1) * 32;
  unsigned short* dst = Vt + ((size_t)(b * HKV_ + kv) * HD_ + cI) * T_ + t0 + rs;
  const unsigned short* srow = &lds[cI * 65 + rs];
  for (int j = 0; j < 32; j += 4) {
    ushort4v v; v.x = srow[j]; v.y = srow[j + 1]; v.z = srow[j + 2]; v.w = srow[j + 3];
    *(ushort4v*)&dst[j] = v;
  }
}

// ---------------- Flash attention v6: GQA head-paired + double-buffered K/V ----------------
// v5's verified dbuf/prefetch structure, plus: each block computes BOTH heads of its KV
// group, so each staged K/V tile feeds 2x the MFMA work (staged traffic halved, stage cost
// amortized). Round-1's failure was a missing "* inv" in the epilogue (absmax 535 == row
// sums), NOT a race — fixed here. Ps is reused twice per kt: per-wave DS ops are in-order
// and Ps is wave-private, so the store->vector-reload pattern is safe; sched_barrier(0)
// fences pin compiler ordering around the cross-lane P exchange (rule #18 analog).
__global__ __launch_bounds__(256, 2) void attn(const unsigned short* __restrict__ Qb,
                                               const unsigned short* __restrict__ Kb,
                                               const unsigned short* __restrict__ Vt,
                                               unsigned short* __restrict__ ctxb) {
  __shared__ __align__(16) unsigned short Ks[2][64 * 128];  // [key][hd], chunk-swizzled
  __shared__ __align__(16) unsigned short Vs[2][128 * 64];  // [hd][key], chunk-swizzled
  __shared__ __align__(16) unsigned short Ps[4][16 * 72];   // per-wave P, stride 72 (pad)
  const int tid = threadIdx.x;
  const int lane = tid & 63;
  const int wv = tid >> 6;
  const int g = lane >> 4;
  const int c = lane & 15;

  const int blk = blockIdx.x;            // 0..511
  const int kv = blk & 7;
  const int idx = blk >> 3;              // 0..63
  const int b = idx & 1;
  const int qbi = idx >> 1;              // 0..31
  const int qb = (qbi < 16) ? qbi : (47 - qbi);  // blk & blk+256 complementary (33 tiles)
  const int nkt = qb + 1;

  const unsigned short* Kh = Kb + (size_t)(b * HKV_ + kv) * T_ * HD_;
  const unsigned short* Vh = Vt + (size_t)(b * HKV_ + kv) * HD_ * T_;
  const float scale = 0.08838834764831845f;  // 1/sqrt(128)

#define STAGE_KV(BF, KT) { \
  _Pragma("unroll") for (int i_ = 0; i_ < 4; i_++) { \
    const int ch_ = wv * 256 + i_ * 64 + lane; \
    const int rK_ = ch_ >> 4, cK_ = ch_ & 15; \
    gll16(Kh + (size_t)((KT) * 64 + rK_) * HD_ + (cK_ ^ (rK_ & 7)) * 8, \
          Ks[BF] + (size_t)(wv * 256 + i_ * 64) * 8); \
    const int rV_ = ch_ >> 3, cV_ = ch_ & 7; \
    gll16(Vh + (size_t)rV_ * T_ + (KT) * 64 + (cV_ ^ (rV_ & 7)) * 8, \
          Vs[BF] + (size_t)(wv * 256 + i_ * 64) * 8); } }

  // Q fragments for both heads of the group (loaded once)
  short8 aq[2][4];
#pragma unroll
  for (int hh = 0; hh < 2; hh++) {
    const unsigned short* Qh =
        Qb + ((size_t)(b * HQ_ + kv * 2 + hh) * T_ + qb * 64 + wv * 16) * HD_;
#pragma unroll
    for (int dk = 0; dk < 4; dk++) aq[hh][dk] = *(const short8*)&Qh[c * HD_ + dk * 32 + g * 8];
  }

  f32x4 acc[2][8];
#pragma unroll
  for (int hh = 0; hh < 2; hh++)
#pragma unroll
    for (int dc = 0; dc < 8; dc++) acc[hh][dc] = (f32x4)0.0f;
  float lp[2][4] = {{0.0f, 0.0f, 0.0f, 0.0f}, {0.0f, 0.0f, 0.0f, 0.0f}};

  STAGE_KV(0, 0);
  __syncthreads();

  for (int kt = 0; kt < nkt; kt++) {
    const int cur = kt & 1;
    if (kt + 1 < nkt) { STAGE_KV(cur ^ 1, kt + 1); }   // block-uniform condition
    __builtin_amdgcn_sched_barrier(0);                 // pin stage-issue before compute

    const bool diag = (kt == nkt - 1);
#pragma unroll
    for (int hh = 0; hh < 2; hh++) {
      f32x4 s[4];
#pragma unroll
      for (int kf = 0; kf < 4; kf++) s[kf] = (f32x4)0.0f;
      __builtin_amdgcn_s_setprio(1);
#pragma unroll
      for (int dk = 0; dk < 4; dk++) {
#pragma unroll
        for (int kf = 0; kf < 4; kf++) {
          short8 bk = *(const short8*)&Ks[cur][(kf * 16 + c) * 128 + ((dk * 4 + g) ^ (c & 7)) * 8];
          s[kf] = __builtin_amdgcn_mfma_f32_16x16x32_bf16(aq[hh][dk], bk, s[kf], 0, 0, 0);
        }
      }
      __builtin_amdgcn_s_setprio(0);

#pragma unroll
      for (int kf = 0; kf < 4; kf++) {
#pragma unroll
        for (int r = 0; r < 4; r++) {
          float pv = __expf(s[kf][r] * scale);
          if (diag) {
            int key = kt * 64 + kf * 16 + c;
            int rowq = qb * 64 + wv * 16 + g * 4 + r;
            if (key > rowq) pv = 0.0f;
          }
          lp[hh][r] += pv;
          Ps[wv][(g * 4 + r) * 72 + kf * 16 + c] = f2bf(pv);
        }
      }
      __builtin_amdgcn_sched_barrier(0);   // P-stores complete-in-order before ap reloads

      short8 ap[2];
      ap[0] = *(const short8*)&Ps[wv][c * 72 + g * 8];
      ap[1] = *(const short8*)&Ps[wv][c * 72 + 32 + g * 8];
      __builtin_amdgcn_sched_barrier(0);   // ap reloads before next hh's P-stores
      __builtin_amdgcn_s_setprio(1);
#pragma unroll
      for (int dc = 0; dc < 8; dc++) {
#pragma unroll
        for (int kf2 = 0; kf2 < 2; kf2++) {
          short8 bv = *(const short8*)&Vs[cur][(dc * 16 + c) * 64 + ((kf2 * 4 + g) ^ (c & 7)) * 8];
          acc[hh][dc] = __builtin_amdgcn_mfma_f32_16x16x32_bf16(ap[kf2], bv, acc[hh][dc], 0, 0, 0);
        }
      }
      __builtin_amdgcn_s_setprio(0);
    }

    __syncthreads();   // drains vmcnt(0): kt+1's tile landed; buf cur free for kt+2
  }

#pragma unroll
  for (int hh = 0; hh < 2; hh++) {
    const int h = kv * 2 + hh;
#pragma unroll
    for (int r = 0; r < 4; r++) {
      float l = lp[hh][r];
      l += __shfl_xor(l, 1); l += __shfl_xor(l, 2);
      l += __shfl_xor(l, 4); l += __shfl_xor(l, 8);
      float inv = 1.0f / l;
      int row = b * T_ + qb * 64 + wv * 16 + g * 4 + r;
#pragma unroll
      for (int dc = 0; dc < 8; dc++)
        ctxb[(size_t)row * (HQ_ * HD_) + h * HD_ + dc * 16 + c] = f2bf(acc[hh][dc][r] * inv);
    }
  }
#undef STAGE_KV
}

extern "C" void kernel_launch(void* const* d_in, const int* in_sizes, int n_in,
                              void* d_out, int out_size, void* d_ws, size_t ws_size,
                              hipStream_t stream) {
  const float* x = (const float*)d_in[0];
  const float* cosT = (const float*)d_in[2];
  const float* sinT = (const float*)d_in[3];
  const float* Wq = (const float*)d_in[4];
  const float* Wk = (const float*)d_in[5];
  const float* Wv = (const float*)d_in[6];
  const float* Wo = (const float*)d_in[7];
  const float* q_scale = (const float*)d_in[8];
  const float* k_scale = (const float*)d_in[9];

  char* ws = (char*)d_ws;
  unsigned short* qkv  = (unsigned short*)(ws + 0);
  unsigned short* ctxb = qkv;                                  // alias: qkv dead before attn
  unsigned short* xb   = (unsigned short*)(ws + 33554432);
  unsigned short* wqkv = (unsigned short*)(ws + 50331648);
  unsigned short* wob  = (unsigned short*)(ws + 67108864);
  unsigned short* Qb   = (unsigned short*)(ws + 75497472);
  unsigned short* Kb   = (unsigned short*)(ws + 92274688);
  unsigned short* Vt   = (unsigned short*)(ws + 100663296);

  cast_all<<<20480, 256, 0, stream>>>(x, Wq, Wk, Wv, Wo, xb, wqkv, wob);
  gemm8<256, 4096, 4096, 2048, true><<<256, 512, 0, stream>>>(xb, wqkv, qkv);
  qk_norm_rope<<<4096, 256, 0, stream>>>(qkv, cosT, sinT, q_scale, k_scale, Qb, Kb);
  v_transpose<<<512, 256, 0, stream>>>(qkv, Vt);
  attn<<<512, 256, 0, stream>>>(Qb, Kb, Vt, ctxb);
  gemm8<128, 4096, 2048, 2048, false><<<256, 512, 0, stream>>>(ctxb, wob, d_out);
}

// Round 7
// 326.193 us; speedup vs baseline: 1.0581x; 1.0581x over previous
//
#include <hip/hip_runtime.h>
#include <cstdint>
#include <cstddef>

#define B_ 2
#define T_ 2048
#define D_ 2048
#define HQ_ 16
#define HKV_ 8
#define HD_ 128

typedef __attribute__((ext_vector_type(8))) short short8;
typedef __attribute__((ext_vector_type(8))) unsigned short ushort8;
typedef __attribute__((ext_vector_type(4))) float f32x4;
typedef __attribute__((ext_vector_type(2))) unsigned short ushort2v;
typedef __attribute__((ext_vector_type(4))) unsigned short ushort4v;
typedef __attribute__((ext_vector_type(2))) float float2v;
typedef __attribute__((ext_vector_type(4))) float float4v;

__device__ __forceinline__ unsigned short f2bf(float f) {
  unsigned int u = __builtin_bit_cast(unsigned int, f);
  u += 0x7fffu + ((u >> 16) & 1u);
  return (unsigned short)(u >> 16);
}
__device__ __forceinline__ float bf2f(unsigned short h) {
  unsigned int u = ((unsigned int)h) << 16;
  return __builtin_bit_cast(float, u);
}

#if defined(__has_builtin)
#if __has_builtin(__builtin_amdgcn_global_load_lds)
#define HAS_GLL 1
#endif
#endif
#ifndef HAS_GLL
#define HAS_GLL 0
#endif

// async global->LDS, 16B per lane; LDS dest = base (wave-uniform) + lane*16
__device__ __forceinline__ void gll16(const void* g, void* l) {
#if HAS_GLL
  __builtin_amdgcn_global_load_lds((const __attribute__((address_space(1))) void*)g,
                                   (__attribute__((address_space(3))) void*)l, 16, 0, 0);
#else
  *(ushort8*)((char*)l + (threadIdx.x & 63) * 16) = *(const ushort8*)g;
#endif
}

// ---------------- fused cast f32 -> bf16, v2: 16 elems/thread, block-uniform tensor ----------------
// All tensor boundaries divide 4096, so each block's 4096-elem range lies in ONE tensor.
__global__ __launch_bounds__(256) void cast_all(const float* __restrict__ x,
                                                const float* __restrict__ wq,
                                                const float* __restrict__ wk,
                                                const float* __restrict__ wv,
                                                const float* __restrict__ wo,
                                                unsigned short* __restrict__ xb,
                                                unsigned short* __restrict__ wqkv,
                                                unsigned short* __restrict__ wob) {
  const int base = blockIdx.x * 4096;
  const float* s;
  unsigned short* d;
  int soff, doff;
  if (base < 8388608)       { s = x;  soff = base;            d = xb;   doff = base; }
  else if (base < 12582912) { s = wq; soff = base - 8388608;  d = wqkv; doff = base - 8388608; }
  else if (base < 14680064) { s = wk; soff = base - 12582912; d = wqkv; doff = base - 8388608; }
  else if (base < 16777216) { s = wv; soff = base - 14680064; d = wqkv; doff = base - 8388608; }
  else                      { s = wo; soff = base - 16777216; d = wob;  doff = base - 16777216; }
#pragma unroll
  for (int k = 0; k < 4; k++) {
    const int off = (k * 256 + threadIdx.x) * 4;
    float4v v = *(const float4v*)(s + soff + off);
    ushort4v o; o.x = f2bf(v.x); o.y = f2bf(v.y); o.z = f2bf(v.z); o.w = f2bf(v.w);
    *(ushort4v*)(d + doff + off) = o;
  }
}

// ================= GEMM v3: BMx256 tile, BK=64, 8 waves, 8-phase pipelined =================
// (unchanged from round 5 — verified; see round-3 proof)
#define PH_SYNC { __builtin_amdgcn_s_barrier(); \
                  asm volatile("s_waitcnt lgkmcnt(0)" ::: "memory"); \
                  __builtin_amdgcn_sched_barrier(0); \
                  __builtin_amdgcn_s_setprio(1); }
#define PH_END  { __builtin_amdgcn_s_setprio(0); \
                  __builtin_amdgcn_s_barrier(); \
                  __builtin_amdgcn_sched_barrier(0); }

#define LDA(BUF, QM) { \
  _Pragma("unroll") for (int ii = 0; ii < BM/64; ii++) { \
    _Pragma("unroll") for (int ks = 0; ks < 2; ks++) \
      a[ii][ks] = *(const short8*)&Abuf[BUF][((QM)*(BM/2) + wm*(BM/4) + ii*16 + c)*64 + (((ks*4+g)^cs)*8)]; } }

#define LDB(BUF, QN, BB) { \
  _Pragma("unroll") for (int jj = 0; jj < 2; jj++) { \
    _Pragma("unroll") for (int ks = 0; ks < 2; ks++) \
      BB[jj][ks] = *(const short8*)&Bbuf[BUF][((QN)*128 + wn*32 + jj*16 + c)*64 + (((ks*4+g)^cs)*8)]; } }

#define MM(QM, QN, BB) { \
  _Pragma("unroll") for (int ii = 0; ii < BM/64; ii++) { \
    _Pragma("unroll") for (int jj = 0; jj < 2; jj++) { \
      f32x4 t_ = __builtin_amdgcn_mfma_f32_16x16x32_bf16(a[ii][0], BB[jj][0], acc[(QM)*(BM/64)+ii][(QN)*2+jj], 0, 0, 0); \
      acc[(QM)*(BM/64)+ii][(QN)*2+jj] = __builtin_amdgcn_mfma_f32_16x16x32_bf16(a[ii][1], BB[jj][1], t_, 0, 0, 0); } } }

template<int BM, int M, int N, int K, bool BF16_OUT>
__global__ __launch_bounds__(512, 2) void gemm8(const unsigned short* __restrict__ A,
                                                const unsigned short* __restrict__ W,
                                                void* __restrict__ Cout) {
  __shared__ __align__(16) unsigned short Abuf[2][BM * 64];
  __shared__ __align__(16) unsigned short Bbuf[2][256 * 64];
  const int tid = threadIdx.x;
  const int lane = tid & 63;
  const int wv = tid >> 6;        // 0..7
  const int g = lane >> 4;        // 0..3
  const int c = lane & 15;
  const int cs = c & 7;
  const int wm = wv >> 2;         // 0..1
  const int wn = wv & 3;          // 0..3

  constexpr int SH_Q = (BM == 256) ? 7 : 6;   // log2(BM/2)
  constexpr int SH_W = SH_Q - 1;              // log2(BM/4)

  constexpr int NT = N / 256;
  constexpr int NWG = (M / BM) * NT;
  constexpr int CHUNK = NWG / 8;  // NWG % 8 == 0 for both instantiations
  const int bid = blockIdx.x;
  const int swz = (bid & 7) * CHUNK + (bid >> 3);
  const int m0 = (swz / NT) * BM;
  const int n0 = (swz % NT) * 256;

  const int prl = wv * 8 + (lane >> 3);   // physical row offset within call
  const int scl = lane & 7;               // stored chunk slot
#define STA(BUF, P0, KO) { \
    int pr_ = (P0) + prl; \
    int lr_ = ((pr_ >> SH_W) & 1) * (BM/2) + ((pr_ >> SH_Q) & 1) * (BM/4) + (pr_ & (BM/4 - 1)); \
    int lc_ = (scl ^ (pr_ & 7)) * 8; \
    gll16(&A[(size_t)(m0 + lr_) * K + (KO) + lc_], &Abuf[BUF][(P0) * 64 + wv * 512]); }
#define STB(BUF, P0, KO) { \
    int pr_ = (P0) + prl; \
    int lr_ = ((pr_ >> 5) & 3) * 64 + ((pr_ >> 7) & 1) * 32 + (pr_ & 31); \
    int lc_ = (scl ^ (pr_ & 7)) * 8; \
    gll16(&W[(size_t)(n0 + lr_) * K + (KO) + lc_], &Bbuf[BUF][(P0) * 64 + wv * 512]); }

#define STAGE_PH2(BUF, KO) { if constexpr (BM == 256) { STA(BUF, 0, KO); STA(BUF, 64, KO); } \
                             else { STA(BUF, 0, KO); } \
                             STB(BUF, 0, KO); STB(BUF, 64, KO); }
#define STAGE_PH3(BUF, KO) { STB(BUF, 128, KO); STB(BUF, 192, KO); }
#define STAGE_PH4(BUF, KO) { if constexpr (BM == 256) { STA(BUF, 128, KO); STA(BUF, 192, KO); } \
                             else { STA(BUF, 64, KO); } }
#define VMW { if constexpr (BM == 256) { asm volatile("s_waitcnt vmcnt(8)" ::: "memory"); } \
              else { asm volatile("s_waitcnt vmcnt(6)" ::: "memory"); } }

  short8 a[BM/64][2], b0[2][2], b1[2][2];
  f32x4 acc[BM/32][4];
#pragma unroll
  for (int i = 0; i < BM/32; i++)
#pragma unroll
    for (int j = 0; j < 4; j++) acc[i][j] = (f32x4)0.0f;

  // prologue: fully stage K-tiles 0 (buf0) and 1 (buf1)
  STAGE_PH2(0, 0); STAGE_PH3(0, 0); STAGE_PH4(0, 0);
  STAGE_PH2(1, 64); STAGE_PH3(1, 64); STAGE_PH4(1, 64);
  VMW;                               // K-tile 0 landed
  __builtin_amdgcn_s_barrier();

  constexpr int NITER = K / 128;   // 16
  for (int it = 0; it < NITER - 1; ++it) {
    const int k2 = it * 128 + 128;   // K-tile 2it+2 -> buf0
    const int k3 = k2 + 64;          // K-tile 2it+3 -> buf1
    LDA(0, 0); LDB(0, 0, b0);
    PH_SYNC; MM(0, 0, b0); PH_END;
    LDB(0, 1, b1);
    STAGE_PH2(0, k2);
    PH_SYNC; MM(0, 1, b1); PH_END;
    LDA(0, 1);
    STAGE_PH3(0, k2);
    PH_SYNC; MM(1, 1, b1); PH_END;
    STAGE_PH4(0, k2);
    VMW;
    PH_SYNC; MM(1, 0, b0); PH_END;
    LDA(1, 0); LDB(1, 0, b0);
    PH_SYNC; MM(0, 0, b0); PH_END;
    LDB(1, 1, b1);
    STAGE_PH2(1, k3);
    PH_SYNC; MM(0, 1, b1); PH_END;
    LDA(1, 1);
    STAGE_PH3(1, k3);
    PH_SYNC; MM(1, 1, b1); PH_END;
    STAGE_PH4(1, k3);
    VMW;
    PH_SYNC; MM(1, 0, b0); PH_END;
  }
  // peeled final iteration (no stages; ph4 drains)
  LDA(0, 0); LDB(0, 0, b0); PH_SYNC; MM(0, 0, b0); PH_END;
  LDB(0, 1, b1);            PH_SYNC; MM(0, 1, b1); PH_END;
  LDA(0, 1);                PH_SYNC; MM(1, 1, b1); PH_END;
  asm volatile("s_waitcnt vmcnt(0)" ::: "memory");
  PH_SYNC; MM(1, 0, b0); PH_END;
  LDA(1, 0); LDB(1, 0, b0); PH_SYNC; MM(0, 0, b0); PH_END;
  LDB(1, 1, b1);            PH_SYNC; MM(0, 1, b1); PH_END;
  LDA(1, 1);                PH_SYNC; MM(1, 1, b1); PH_END;
  PH_SYNC; MM(1, 0, b0); PH_END;

  // epilogue: C/D layout col=lane&15, row=g*4+r (verified)
#pragma unroll
  for (int I = 0; I < BM/32; I++)
#pragma unroll
    for (int J = 0; J < 4; J++)
#pragma unroll
      for (int r = 0; r < 4; r++) {
        int row = m0 + wm * (BM/2) + I * 16 + g * 4 + r;
        int col = n0 + wn * 64 + J * 16 + c;
        if (BF16_OUT)
          ((unsigned short*)Cout)[(size_t)row * N + col] = f2bf(acc[I][J][r]);
        else
          ((float*)Cout)[(size_t)row * N + col] = acc[I][J][r];
      }
#undef STA
#undef STB
#undef STAGE_PH2
#undef STAGE_PH3
#undef STAGE_PH4
#undef VMW
}

// ---------------- fused RMSNorm+RoPE (blocks 0..4095) and V-transpose (blocks 4096..4607) ----------------
// Both paths byte-identical to the verified standalone kernels; fusion removes one launch.
__global__ __launch_bounds__(256) void rope_and_vt(const unsigned short* __restrict__ qkv,
                                                   const float* __restrict__ cosT,
                                                   const float* __restrict__ sinT,
                                                   const float* __restrict__ q_scale,
                                                   const float* __restrict__ k_scale,
                                                   unsigned short* __restrict__ Qb,
                                                   unsigned short* __restrict__ Kb,
                                                   unsigned short* __restrict__ Vt) {
  __shared__ unsigned short lds[128 * 65];
  const int tid = threadIdx.x;
  if (blockIdx.x < 4096) {
    // ---- RMSNorm + RoPE path ----
    const int lane = tid & 63;
    const int wvq = tid >> 6;
    const int row = blockIdx.x;   // b*T + t
    const int b = row >> 11;
    const int t = row & 2047;
    const int d0 = lane * 2;

    const float2v cs = *(const float2v*)&cosT[t * 128 + d0];
    const float2v sn = *(const float2v*)&sinT[t * 128 + d0];
    const float2v qsc = *(const float2v*)&q_scale[d0];
    const float2v ksc = *(const float2v*)&k_scale[d0];
    const float sgn = (lane < 32) ? -1.0f : 1.0f;
    const unsigned short* base = qkv + (size_t)row * 4096;

#pragma unroll
    for (int s6 = 0; s6 < 6; s6++) {
      const int slot = wvq * 6 + s6;
      const bool isQ = slot < 16;
      const unsigned short* src = base + (isQ ? slot * 128 : 2048 + (slot - 16) * 128);
      ushort2v u = *(const ushort2v*)&src[d0];
      float x0 = bf2f(u.x), x1 = bf2f(u.y);
      float ss = x0 * x0 + x1 * x1;
      ss += __shfl_xor(ss, 1);  ss += __shfl_xor(ss, 2);  ss += __shfl_xor(ss, 4);
      ss += __shfl_xor(ss, 8);  ss += __shfl_xor(ss, 16); ss += __shfl_xor(ss, 32);
      float rinv = rsqrtf(ss * (1.0f / 128.0f) + 1e-6f);
      float2v scv = isQ ? qsc : ksc;
      float xn0 = x0 * rinv * scv.x;
      float xn1 = x1 * rinv * scv.y;
      float o0 = __shfl_xor(xn0, 32);
      float o1 = __shfl_xor(xn1, 32);
      float r0v = xn0 * cs.x + sgn * o0 * sn.x;
      float r1v = xn1 * cs.y + sgn * o1 * sn.y;
      ushort2v out; out.x = f2bf(r0v); out.y = f2bf(r1v);
      unsigned short* dst;
      if (isQ) dst = Qb + ((size_t)(b * HQ_ + slot) * T_ + t) * HD_;
      else     dst = Kb + ((size_t)(b * HKV_ + (slot - 16)) * T_ + t) * HD_;
      *(ushort2v*)&dst[d0] = out;
    }
  } else {
    // ---- V transpose path: (b,t,kv,d) -> Vt[b,kv,d,t] ----
    const int blk = blockIdx.x - 4096;     // 0..511
    const int tblk = blk & 31;
    const int kv = (blk >> 5) & 7;
    const int b = blk >> 8;
    const int t0 = tblk * 64;
    const int r = tid >> 2;
    const int seg = tid & 3;
    const unsigned short* src = qkv + (size_t)(b * T_ + t0 + r) * 4096 + 3072 + kv * 128;
    for (int i = 0; i < 4; i++) {
      int cc = seg * 32 + i * 8;
      ushort8 v = *(const ushort8*)&src[cc];
      for (int q = 0; q < 8; q++) lds[(cc + q) * 65 + r] = v[q];
    }
    __syncthreads();
    const int cI = tid >> 1;
    const int rs = (tid & 1) * 32;
    unsigned short* dst = Vt + ((size_t)(b * HKV_ + kv) * HD_ + cI) * T_ + t0 + rs;
    const unsigned short* srow = &lds[cI * 65 + rs];
    for (int j = 0; j < 32; j += 4) {
      ushort4v v; v.x = srow[j]; v.y = srow[j + 1]; v.z = srow[j + 2]; v.w = srow[j + 3];
      *(ushort4v*)&dst[j] = v;
    }
  }
}

// ---------------- Flash attention v5 (reverted from v6): double-buffered K/V, uniform work ----------------
// v6 lesson: variable per-block work (head-pairing) relied on dispatch co-location and
// collapsed occupancy (20%->12%) -> +16 us. Uniform 33-tiles-per-block restored.
__global__ __launch_bounds__(256) void attn(const unsigned short* __restrict__ Qb,
                                            const unsigned short* __restrict__ Kb,
                                            const unsigned short* __restrict__ Vt,
                                            unsigned short* __restrict__ ctxb) {
  __shared__ __align__(16) unsigned short Ks[2][64 * 128];  // [key][hd], chunk-swizzled
  __shared__ __align__(16) unsigned short Vs[2][128 * 64];  // [hd][key], chunk-swizzled
  __shared__ __align__(16) unsigned short Ps[4][16 * 72];   // per-wave P, stride 72 (pad)
  const int tid = threadIdx.x;
  const int lane = tid & 63;
  const int wv = tid >> 6;
  const int g = lane >> 4;
  const int c = lane & 15;

  const int blk = blockIdx.x;            // 0..511
  const int kv = blk & 7;
  const int idx = blk >> 3;              // 0..63
  const int p = idx >> 2;                // 0..15 pair index
  const int b = (idx >> 1) & 1;
  const int h = kv * 2 + (idx & 1);

  const unsigned short* Kh = Kb + (size_t)(b * HKV_ + kv) * T_ * HD_;
  const unsigned short* Vh = Vt + (size_t)(b * HKV_ + kv) * HD_ * T_;
  const float scale = 0.08838834764831845f;  // 1/sqrt(128)

#define STAGE_KV(BF, KT) { \
  _Pragma("unroll") for (int i_ = 0; i_ < 4; i_++) { \
    const int ch_ = wv * 256 + i_ * 64 + lane; \
    const int rK_ = ch_ >> 4, cK_ = ch_ & 15; \
    gll16(Kh + (size_t)((KT) * 64 + rK_) * HD_ + (cK_ ^ (rK_ & 7)) * 8, \
          Ks[BF] + (size_t)(wv * 256 + i_ * 64) * 8); \
    const int rV_ = ch_ >> 3, cV_ = ch_ & 7; \
    gll16(Vh + (size_t)rV_ * T_ + (KT) * 64 + (cV_ ^ (rV_ & 7)) * 8, \
          Vs[BF] + (size_t)(wv * 256 + i_ * 64) * 8); } }

  for (int ph = 0; ph < 2; ph++) {
    const int qb = ph ? (31 - p) : p;    // 64-row q-block index
    const int nkt = qb + 1;
    const unsigned short* Qh = Qb + ((size_t)(b * HQ_ + h) * T_ + qb * 64 + wv * 16) * HD_;

    short8 aq[4];
#pragma unroll
    for (int dk = 0; dk < 4; dk++) aq[dk] = *(const short8*)&Qh[c * HD_ + dk * 32 + g * 8];

    f32x4 acc[8];
#pragma unroll
    for (int dc = 0; dc < 8; dc++) acc[dc] = (f32x4)0.0f;
    float lp[4] = {0.0f, 0.0f, 0.0f, 0.0f};

    // prologue: stage kt=0 into buf0 (prev ph's last barrier protects buf reuse)
    STAGE_KV(0, 0);
    __syncthreads();

    for (int kt = 0; kt < nkt; kt++) {
      const int cur = kt & 1;
      if (kt + 1 < nkt) { STAGE_KV(cur ^ 1, kt + 1); }   // block-uniform condition
      __builtin_amdgcn_sched_barrier(0);                 // pin stage-issue before compute

      f32x4 s[4];
#pragma unroll
      for (int kf = 0; kf < 4; kf++) s[kf] = (f32x4)0.0f;
      __builtin_amdgcn_s_setprio(1);
#pragma unroll
      for (int dk = 0; dk < 4; dk++) {
#pragma unroll
        for (int kf = 0; kf < 4; kf++) {
          short8 bk = *(const short8*)&Ks[cur][(kf * 16 + c) * 128 + ((dk * 4 + g) ^ (c & 7)) * 8];
          s[kf] = __builtin_amdgcn_mfma_f32_16x16x32_bf16(aq[dk], bk, s[kf], 0, 0, 0);
        }
      }
      __builtin_amdgcn_s_setprio(0);

      const bool diag = (kt == nkt - 1);
#pragma unroll
      for (int kf = 0; kf < 4; kf++) {
#pragma unroll
        for (int r = 0; r < 4; r++) {
          float pv = __expf(s[kf][r] * scale);
          if (diag) {
            int key = kt * 64 + kf * 16 + c;
            int rowq = qb * 64 + wv * 16 + g * 4 + r;
            if (key > rowq) pv = 0.0f;
          }
          lp[r] += pv;
          Ps[wv][(g * 4 + r) * 72 + kf * 16 + c] = f2bf(pv);
        }
      }

      short8 ap[2];
      ap[0] = *(const short8*)&Ps[wv][c * 72 + g * 8];
      ap[1] = *(const short8*)&Ps[wv][c * 72 + 32 + g * 8];
      __builtin_amdgcn_s_setprio(1);
#pragma unroll
      for (int dc = 0; dc < 8; dc++) {
#pragma unroll
        for (int kf2 = 0; kf2 < 2; kf2++) {
          short8 bv = *(const short8*)&Vs[cur][(dc * 16 + c) * 64 + ((kf2 * 4 + g) ^ (c & 7)) * 8];
          acc[dc] = __builtin_amdgcn_mfma_f32_16x16x32_bf16(ap[kf2], bv, acc[dc], 0, 0, 0);
        }
      }
      __builtin_amdgcn_s_setprio(0);

      __syncthreads();   // drains vmcnt(0): kt+1's tile landed; buf cur free for kt+2
    }

#pragma unroll
    for (int r = 0; r < 4; r++) {
      float l = lp[r];
      l += __shfl_xor(l, 1); l += __shfl_xor(l, 2);
      l += __shfl_xor(l, 4); l += __shfl_xor(l, 8);
      float inv = 1.0f / l;
      int row = b * T_ + qb * 64 + wv * 16 + g * 4 + r;
#pragma unroll
      for (int dc = 0; dc < 8; dc++)
        ctxb[(size_t)row * (HQ_ * HD_) + h * HD_ + dc * 16 + c] = f2bf(acc[dc][r] * inv);
    }
  }
#undef STAGE_KV
}

extern "C" void kernel_launch(void* const* d_in, const int* in_sizes, int n_in,
                              void* d_out, int out_size, void* d_ws, size_t ws_size,
                              hipStream_t stream) {
  const float* x = (const float*)d_in[0];
  const float* cosT = (const float*)d_in[2];
  const float* sinT = (const float*)d_in[3];
  const float* Wq = (const float*)d_in[4];
  const float* Wk = (const float*)d_in[5];
  const float* Wv = (const float*)d_in[6];
  const float* Wo = (const float*)d_in[7];
  const float* q_scale = (const float*)d_in[8];
  const float* k_scale = (const float*)d_in[9];

  char* ws = (char*)d_ws;
  unsigned short* qkv  = (unsigned short*)(ws + 0);
  unsigned short* ctxb = qkv;                                  // alias: qkv dead before attn
  unsigned short* xb   = (unsigned short*)(ws + 33554432);
  unsigned short* wqkv = (unsigned short*)(ws + 50331648);
  unsigned short* wob  = (unsigned short*)(ws + 67108864);
  unsigned short* Qb   = (unsigned short*)(ws + 75497472);
  unsigned short* Kb   = (unsigned short*)(ws + 92274688);
  unsigned short* Vt   = (unsigned short*)(ws + 100663296);

  cast_all<<<5120, 256, 0, stream>>>(x, Wq, Wk, Wv, Wo, xb, wqkv, wob);
  gemm8<256, 4096, 4096, 2048, true><<<256, 512, 0, stream>>>(xb, wqkv, qkv);
  rope_and_vt<<<4608, 256, 0, stream>>>(qkv, cosT, sinT, q_scale, k_scale, Qb, Kb, Vt);
  attn<<<512, 256, 0, stream>>>(Qb, Kb, Vt, ctxb);
  gemm8<128, 4096, 2048, 2048, false><<<256, 512, 0, stream>>>(ctxb, wob, d_out);
}